// Round 9
// baseline (158.038 us; speedup 1.0000x reference)
//
#include <hip/hip_runtime.h>
#include <math.h>

#define PP 4
#define BB 32
#define PB (PP * BB)
#define NN 2048
#define MM 512
#define DLAT 128
#define BETA_C 1e-3f
#define BIGV 1e9f
#define SENT 1e8f
#define THREADS 256
#define NWAVE 4
#define QCHUNKS 4
#define CCHUNKS 4
#define QCH (NN / QCHUNKS)    // 512 n-range per quality chunk
#define CCH (MM / CCHUNKS)    // 128 y per coverage chunk
#define TOTALBLK (BB * PP * (QCHUNKS + CCHUNKS))   // 1024
#define XMAX (NN + 16)

// Device-global scratch. Planes of PB floats:
// 0..3 qual[z] | 4..7 cov[c] | 8..11 nx[z] | 12..15 ny[c]
// Every plane cell written by exactly one block each launch -> replay-safe.
__device__ float g_ws[16 * PB];
__device__ int g_done;   // zero at load; last block resets to 0 each launch

__device__ __forceinline__ int wave_compact_slot(bool sel, int* s_cnt, int lane) {
    unsigned long long bal = __ballot(sel);
    int lofs = __popcll(bal & ((1ull << lane) - 1ull));
    int base = 0;
    if (lane == 0 && bal) base = atomicAdd(s_cnt, __popcll(bal));
    base = __shfl(base, 0);
    return base + lofs;
}

// One block per (b, i, z). z<QCHUNKS: quality x-chunk z; else coverage y-chunk.
// 1024 blocks x 256 thr -> 4 blocks/CU -> 4 waves/SIMD, fine-grained balance.
// The LAST block to finish also runs the finalize (fused, saves a launch).
__global__ __launch_bounds__(THREADS) void fused_kernel(
    const float* __restrict__ ipt,    // (B,N,3)
    const float* __restrict__ opt,    // (P,B,M,3)
    const float* __restrict__ trans,  // (P,B,3)
    const float* __restrict__ rots,   // (P,B,4)
    const int*   __restrict__ idx,    // (B,N)
    const float* __restrict__ probs,  // (P,B,1)
    const float* __restrict__ mu,     // (B,DLAT)
    const float* __restrict__ logvar, // (B,DLAT)
    float* __restrict__ out)
{
    const int b = blockIdx.x;
    const int i = blockIdx.y;
    const int z = blockIdx.z;
    const int tid = threadIdx.x;
    const int lane = tid & 63;
    const int w = tid >> 6;

    __shared__ float Rm[12];
    __shared__ int s_nx, s_ny, s_last;
    __shared__ __align__(16) float syx[MM], syy[MM], syz[MM];
    __shared__ __align__(16) float sxx[XMAX], sxy[XMAX], sxz[XMAX];
    __shared__ float pmin[NWAVE][128];
    __shared__ float red[NWAVE];

    if (tid == 0) {
        s_nx = 0;
        s_ny = 0;
        const float* q = rots + (i * BB + b) * 4;
        float qw = q[0], qx = q[1], qy = q[2], qz = q[3];
        float inv = 1.0f / sqrtf(qw * qw + qx * qx + qy * qy + qz * qz);
        qw *= inv; qx *= inv; qy *= inv; qz *= inv;
        Rm[0] = 1.0f - 2.0f * (qy * qy + qz * qz);
        Rm[1] = 2.0f * (qx * qy - qw * qz);
        Rm[2] = 2.0f * (qx * qz + qw * qy);
        Rm[3] = 2.0f * (qx * qy + qw * qz);
        Rm[4] = 1.0f - 2.0f * (qx * qx + qz * qz);
        Rm[5] = 2.0f * (qy * qz - qw * qx);
        Rm[6] = 2.0f * (qx * qz - qw * qy);
        Rm[7] = 2.0f * (qy * qz + qw * qx);
        Rm[8] = 1.0f - 2.0f * (qx * qx + qy * qy);
        const float* t = trans + (i * BB + b) * 3;
        Rm[9] = t[0]; Rm[10] = t[1]; Rm[11] = t[2];
    }
    __syncthreads();

    const float R0 = Rm[0], R1 = Rm[1], R2 = Rm[2];
    const float R3 = Rm[3], R4 = Rm[4], R5 = Rm[5];
    const float R6 = Rm[6], R7 = Rm[7], R8 = Rm[8];
    const float t0 = Rm[9], t1 = Rm[10], t2 = Rm[11];
    const size_t optbase = ((size_t)i * BB + b) * MM;
    const int pb = i * BB + b;

    float sum = 0.0f;

    if (z < QCHUNKS) {
        // ---------------- quality x-chunk z ----------------
        for (int m = tid; m < MM; m += THREADS) {       // stage all y, SoA
            const float* y = opt + (optbase + m) * 3;
            float yx = y[0], yy = y[1], yz = y[2];
            bool v = (yx != 0.0f) | (yy != 0.0f) | (yz != 0.0f);
            if (!v) { yx = SENT; yy = SENT; yz = SENT; }
            syx[m] = yx; syy[m] = yy; syz[m] = yz;
        }
        const int n0 = z * QCH;                         // compact this n-range
        for (int n = n0 + tid; n < n0 + QCH; n += THREADS) {
            const float* p = ipt + ((size_t)b * NN + n) * 3;
            float px = p[0], py = p[1], pz = p[2];
            bool nz = (px != 0.0f) | (py != 0.0f) | (pz != 0.0f);
            bool sel = nz && (idx[b * NN + n] == i);
            int pos = wave_compact_slot(sel, &s_nx, lane);
            if (sel) {
                px -= t0; py -= t1; pz -= t2;
                sxx[pos] = R0 * px + R1 * py + R2 * pz;
                sxy[pos] = R3 * px + R4 * py + R5 * pz;
                sxz[pos] = R6 * px + R7 * py + R8 * pz;
            }
        }
        __syncthreads();
        const int nxc = s_nx;
        const int y0 = w * (MM / NWAVE);                // wave's 128-y stream

        for (int base = 0; base < nxc; base += 128) {   // typically one pass
            float px[2], py[2], pz[2], mn[2];
            bool act[2];
#pragma unroll
            for (int s = 0; s < 2; ++s) {
                int k = base + s * 64 + lane;
                act[s] = (k < nxc);
                px[s] = act[s] ? sxx[k] : SENT;
                py[s] = act[s] ? sxy[k] : SENT;
                pz[s] = act[s] ? sxz[k] : SENT;
                mn[s] = BIGV;
            }
            for (int j = 0; j < MM / NWAVE; j += 4) {   // wave-uniform broadcast b128
                float4 yx = *reinterpret_cast<const float4*>(syx + y0 + j);
                float4 yy = *reinterpret_cast<const float4*>(syy + y0 + j);
                float4 yz = *reinterpret_cast<const float4*>(syz + y0 + j);
#pragma unroll
                for (int s = 0; s < 2; ++s) {
                    float dx0 = px[s] - yx.x, dy0 = py[s] - yy.x, dz0 = pz[s] - yz.x;
                    float dx1 = px[s] - yx.y, dy1 = py[s] - yy.y, dz1 = pz[s] - yz.y;
                    float dx2 = px[s] - yx.z, dy2 = py[s] - yy.z, dz2 = pz[s] - yz.z;
                    float dx3 = px[s] - yx.w, dy3 = py[s] - yy.w, dz3 = pz[s] - yz.w;
                    float d0 = dx0 * dx0 + dy0 * dy0 + dz0 * dz0;
                    float d1 = dx1 * dx1 + dy1 * dy1 + dz1 * dz1;
                    float d2 = dx2 * dx2 + dy2 * dy2 + dz2 * dz2;
                    float d3 = dx3 * dx3 + dy3 * dy3 + dz3 * dz3;
                    mn[s] = fminf(mn[s], fminf(fminf(d0, d1), fminf(d2, d3)));
                }
            }
#pragma unroll
            for (int s = 0; s < 2; ++s) pmin[w][s * 64 + lane] = mn[s];
            __syncthreads();
            if (tid < 128 && base + tid < nxc) {
                float m = pmin[0][tid];
#pragma unroll
                for (int ww = 1; ww < NWAVE; ++ww) m = fminf(m, pmin[ww][tid]);
                sum += m;
            }
            __syncthreads();
        }

        for (int off = 32; off > 0; off >>= 1) sum += __shfl_down(sum, off);
        if (lane == 0) red[w] = sum;
        __syncthreads();
        if (tid == 0) {
            float tot = red[0] + red[1] + red[2] + red[3];
            g_ws[(0 + z) * PB + pb] = tot;              // qual partial
            g_ws[(8 + z) * PB + pb] = (float)s_nx;      // nx partial
        }
    } else {
        // ---------------- coverage y-chunk c ----------------
        const int c = z - QCHUNKS;
        if (tid < CCH) {                                // stage 128 y (waves 0-1)
            const float* y = opt + (optbase + c * CCH + tid) * 3;
            float yx = y[0], yy = y[1], yz = y[2];
            bool v = (yx != 0.0f) | (yy != 0.0f) | (yz != 0.0f);
            if (!v) { yx = SENT; yy = SENT; yz = SENT; }
            syx[tid] = yx; syy[tid] = yy; syz[tid] = yz;
            unsigned long long bal = __ballot(v);
            if (lane == 0) atomicAdd(&s_ny, __popcll(bal));
        }
        for (int n = tid; n < NN; n += THREADS) {       // compact FULL x
            const float* p = ipt + ((size_t)b * NN + n) * 3;
            float px = p[0], py = p[1], pz = p[2];
            bool nz = (px != 0.0f) | (py != 0.0f) | (pz != 0.0f);
            bool sel = nz && (idx[b * NN + n] == i);
            int pos = wave_compact_slot(sel, &s_nx, lane);
            if (sel) {
                px -= t0; py -= t1; pz -= t2;
                sxx[pos] = R0 * px + R1 * py + R2 * pz;
                sxy[pos] = R3 * px + R4 * py + R5 * pz;
                sxz[pos] = R6 * px + R7 * py + R8 * pz;
            }
        }
        __syncthreads();
        const int nx = s_nx;
        const int ny = s_ny;
        const int nx16 = (nx + 15) & ~15;               // 4 wave-quarters, each %4==0
        if (tid < nx16 - nx) {
            sxx[nx + tid] = SENT; sxy[nx + tid] = SENT; sxz[nx + tid] = SENT;
        }
        __syncthreads();

        float qx[2], qy[2], qz[2], mn[2];
#pragma unroll
        for (int s = 0; s < 2; ++s) {                   // lane's 2 y slots
            int j = s * 64 + lane;
            qx[s] = syx[j]; qy[s] = syy[j]; qz[s] = syz[j];
            mn[s] = BIGV;
        }
        const int q = nx16 / NWAVE;
        const int x0 = w * q;
        for (int k = 0; k < q; k += 4) {                // wave-uniform broadcast b128
            float4 xx = *reinterpret_cast<const float4*>(sxx + x0 + k);
            float4 xy = *reinterpret_cast<const float4*>(sxy + x0 + k);
            float4 xz = *reinterpret_cast<const float4*>(sxz + x0 + k);
#pragma unroll
            for (int s = 0; s < 2; ++s) {
                float dx0 = qx[s] - xx.x, dy0 = qy[s] - xy.x, dz0 = qz[s] - xz.x;
                float dx1 = qx[s] - xx.y, dy1 = qy[s] - xy.y, dz1 = qz[s] - xz.y;
                float dx2 = qx[s] - xx.z, dy2 = qy[s] - xy.z, dz2 = qz[s] - xz.z;
                float dx3 = qx[s] - xx.w, dy3 = qy[s] - xy.w, dz3 = qz[s] - xz.w;
                float d0 = dx0 * dx0 + dy0 * dy0 + dz0 * dz0;
                float d1 = dx1 * dx1 + dy1 * dy1 + dz1 * dz1;
                float d2 = dx2 * dx2 + dy2 * dy2 + dz2 * dz2;
                float d3 = dx3 * dx3 + dy3 * dy3 + dz3 * dz3;
                mn[s] = fminf(mn[s], fminf(fminf(d0, d1), fminf(d2, d3)));
            }
        }
#pragma unroll
        for (int s = 0; s < 2; ++s) pmin[w][s * 64 + lane] = mn[s];   // BIGV if q==0
        __syncthreads();
        if (tid < CCH && syx[tid] != SENT) {            // valid y only
            float m = pmin[0][tid];
#pragma unroll
            for (int ww = 1; ww < NWAVE; ++ww) m = fminf(m, pmin[ww][tid]);
            sum += m;                                   // nx==0 -> BIGV, gated in finalize
        }
        __syncthreads();

        for (int off = 32; off > 0; off >>= 1) sum += __shfl_down(sum, off);
        if (lane == 0) red[w] = sum;
        __syncthreads();
        if (tid == 0) {
            float tot = red[0] + red[1] + red[2] + red[3];
            g_ws[(4 + c) * PB + pb] = tot;              // cov partial
            g_ws[(12 + c) * PB + pb] = (float)ny;       // ny partial
        }
    }

    // ---- fused finalize: last block to finish does it (device-scope handoff) ----
    __threadfence();                                    // release g_ws stores
    if (tid == 0) {
        int prev = atomicAdd(&g_done, 1);
        s_last = (prev == TOTALBLK - 1) ? 1 : 0;
        if (s_last) atomicExch(&g_done, 0);             // reset for next launch
    }
    __syncthreads();
    if (!s_last) return;
    __threadfence();                                    // acquire all blocks' g_ws

    // KL over B*DLAT, float4-vectorized
    const float4* mu4 = reinterpret_cast<const float4*>(mu);
    const float4* lv4 = reinterpret_cast<const float4*>(logvar);
    float kls = 0.0f;
    for (int t = tid; t < BB * DLAT / 4; t += THREADS) {
        float4 m4 = mu4[t], l4 = lv4[t];
        kls += (1.0f + l4.x - m4.x * m4.x - expf(l4.x))
             + (1.0f + l4.y - m4.y * m4.y - expf(l4.y))
             + (1.0f + l4.z - m4.z * m4.z - expf(l4.z))
             + (1.0f + l4.w - m4.w * m4.w - expf(l4.w));
    }
    for (int off = 32; off > 0; off >>= 1) kls += __shfl_down(kls, off);
    if (lane == 0) red[w] = kls;

    // reuse staging LDS for per-(i,b) weighted terms
    float* s_wq = syx;
    float* s_wc = syy;
    float* s_val = syz;
    if (tid < PB) {
        float qs  = g_ws[0 * PB + tid] + g_ws[1 * PB + tid] + g_ws[2 * PB + tid] + g_ws[3 * PB + tid];
        float cs  = g_ws[4 * PB + tid] + g_ws[5 * PB + tid] + g_ws[6 * PB + tid] + g_ws[7 * PB + tid];
        float nxf = g_ws[8 * PB + tid] + g_ws[9 * PB + tid] + g_ws[10 * PB + tid] + g_ws[11 * PB + tid];
        float nyf = g_ws[12 * PB + tid] + g_ws[13 * PB + tid] + g_ws[14 * PB + tid] + g_ws[15 * PB + tid];
        bool valid = (nxf > 0.0f) && (nyf > 0.0f);
        float wgt = valid ? probs[tid] : 0.0f;
        s_wq[tid] = wgt * (qs / fmaxf(nxf, 1.0f));
        s_wc[tid] = wgt * (cs / fmaxf(nyf, 1.0f));
        s_val[tid] = valid ? 1.0f : 0.0f;
    }
    __syncthreads();

    if (tid == 0) {
        float kld = -0.5f * (red[0] + red[1] + red[2] + red[3]) / (float)BB;
        float ch = 0.0f, cov = 0.0f, qu = 0.0f, num = 0.0f;
        for (int ii = 0; ii < PP; ++ii) {
            float sq = 0.0f, sc = 0.0f, n = 0.0f;
            for (int bb = 0; bb < BB; ++bb) {
                sq += s_wq[ii * BB + bb];
                sc += s_wc[ii * BB + bb];
                n += s_val[ii * BB + bb];
            }
            float has = (n > 0.0f) ? 1.0f : 0.0f;
            float invn = has / fmaxf(n, 1.0f);
            qu += sq * invn;
            cov += sc * invn;
            ch += (sq + sc) * invn;
            num += has;
        }
        float invnum = 1.0f / fmaxf(num, 1.0f);
        float cds = ch * invnum;
        out[0] = cds + BETA_C * kld;
        out[1] = cds;
        out[2] = cov * invnum;
        out[3] = qu * invnum;
        out[4] = kld;
    }
}

extern "C" void kernel_launch(void* const* d_in, const int* in_sizes, int n_in,
                              void* d_out, int out_size, void* d_ws, size_t ws_size,
                              hipStream_t stream) {
    const float* ipt    = (const float*)d_in[0];
    const float* opt    = (const float*)d_in[1];
    const float* trans  = (const float*)d_in[2];
    const float* rots   = (const float*)d_in[3];
    const float* probs  = (const float*)d_in[4];
    const int*   idx    = (const int*)d_in[5];
    const float* mu     = (const float*)d_in[6];
    const float* logvar = (const float*)d_in[7];
    float* out = (float*)d_out;
    (void)d_ws; (void)ws_size; (void)in_sizes; (void)n_in; (void)out_size;

    dim3 grid(BB, PP, QCHUNKS + CCHUNKS);
    fused_kernel<<<grid, THREADS, 0, stream>>>(ipt, opt, trans, rots, idx,
                                               probs, mu, logvar, out);
}

// Round 10
// 92.216 us; speedup vs baseline: 1.7138x; 1.7138x over previous
//
#include <hip/hip_runtime.h>
#include <math.h>

#define PP 4
#define BB 32
#define PB (PP * BB)
#define NN 2048
#define MM 512
#define DLAT 128
#define BETA_C 1e-3f
#define BIGV 1e9f
#define SENT 1e8f
#define THREADS 512
#define NWAVE 8
#define QCHUNKS 4
#define CCHUNKS 4
#define QCH (NN / QCHUNKS)    // 512 n-range per quality chunk
#define CCH (MM / CCHUNKS)    // 128 y per coverage chunk
#define XMAX (NN + 32)

// Device-global scratch, disjoint slot per chunk-block (no atomics, no init).
// Planes of PB floats: 0..3 qual[z] | 4..7 cov[c] | 8..11 nx[z] | 12..15 ny[c]
// Every plane cell written by exactly one block each launch -> replay-safe.
__device__ float g_ws[16 * PB];

__device__ __forceinline__ int wave_compact_slot(bool sel, int* s_cnt, int lane) {
    unsigned long long bal = __ballot(sel);
    int lofs = __popcll(bal & ((1ull << lane) - 1ull));
    int base = 0;
    if (lane == 0 && bal) base = atomicAdd(s_cnt, __popcll(bal));
    base = __shfl(base, 0);
    return base + lofs;
}

// One block per (b, i, z). z<QCHUNKS: quality x-chunk; else coverage y-chunk.
// 1024 blocks x 512 thr (VGPR capped for 8 waves/SIMD) -> 4 blocks/CU ->
// 32 waves/CU full occupancy. Wave-split streaming + pmin combine (round-8
// structure). NO device-scope fences (round-9 lesson: per-block threadfence
// = L2 writeback on non-coherent XCDs, catastrophic).
__global__ __launch_bounds__(THREADS, 8) void parts_kernel(
    const float* __restrict__ ipt,    // (B,N,3)
    const float* __restrict__ opt,    // (P,B,M,3)
    const float* __restrict__ trans,  // (P,B,3)
    const float* __restrict__ rots,   // (P,B,4)
    const int*   __restrict__ idx)    // (B,N)
{
    const int b = blockIdx.x;
    const int i = blockIdx.y;
    const int z = blockIdx.z;
    const int tid = threadIdx.x;
    const int lane = tid & 63;
    const int w = tid >> 6;

    __shared__ float Rm[12];
    __shared__ int s_nx, s_ny;
    __shared__ __align__(16) float syx[MM], syy[MM], syz[MM];
    __shared__ __align__(16) float sxx[XMAX], sxy[XMAX], sxz[XMAX];
    __shared__ float pmin[NWAVE][128];
    __shared__ float red[NWAVE];

    if (tid == 0) {
        s_nx = 0;
        s_ny = 0;
        const float* q = rots + (i * BB + b) * 4;
        float qw = q[0], qx = q[1], qy = q[2], qz = q[3];
        float inv = 1.0f / sqrtf(qw * qw + qx * qx + qy * qy + qz * qz);
        qw *= inv; qx *= inv; qy *= inv; qz *= inv;
        Rm[0] = 1.0f - 2.0f * (qy * qy + qz * qz);
        Rm[1] = 2.0f * (qx * qy - qw * qz);
        Rm[2] = 2.0f * (qx * qz + qw * qy);
        Rm[3] = 2.0f * (qx * qy + qw * qz);
        Rm[4] = 1.0f - 2.0f * (qx * qx + qz * qz);
        Rm[5] = 2.0f * (qy * qz - qw * qx);
        Rm[6] = 2.0f * (qx * qz - qw * qy);
        Rm[7] = 2.0f * (qy * qz + qw * qx);
        Rm[8] = 1.0f - 2.0f * (qx * qx + qy * qy);
        const float* t = trans + (i * BB + b) * 3;
        Rm[9] = t[0]; Rm[10] = t[1]; Rm[11] = t[2];
    }
    __syncthreads();

    const float R0 = Rm[0], R1 = Rm[1], R2 = Rm[2];
    const float R3 = Rm[3], R4 = Rm[4], R5 = Rm[5];
    const float R6 = Rm[6], R7 = Rm[7], R8 = Rm[8];
    const float t0 = Rm[9], t1 = Rm[10], t2 = Rm[11];
    const size_t optbase = ((size_t)i * BB + b) * MM;
    const int pb = i * BB + b;

    float sum = 0.0f;

    if (z < QCHUNKS) {
        // ---------------- quality x-chunk z ----------------
        for (int m = tid; m < MM; m += THREADS) {       // stage all y, SoA
            const float* y = opt + (optbase + m) * 3;
            float yx = y[0], yy = y[1], yz = y[2];
            bool v = (yx != 0.0f) | (yy != 0.0f) | (yz != 0.0f);
            if (!v) { yx = SENT; yy = SENT; yz = SENT; }
            syx[m] = yx; syy[m] = yy; syz[m] = yz;
        }
        const int n0 = z * QCH;                         // compact this n-range
        for (int n = n0 + tid; n < n0 + QCH; n += THREADS) {
            const float* p = ipt + ((size_t)b * NN + n) * 3;
            float px = p[0], py = p[1], pz = p[2];
            bool nz = (px != 0.0f) | (py != 0.0f) | (pz != 0.0f);
            bool sel = nz && (idx[b * NN + n] == i);
            int pos = wave_compact_slot(sel, &s_nx, lane);
            if (sel) {
                px -= t0; py -= t1; pz -= t2;
                sxx[pos] = R0 * px + R1 * py + R2 * pz;
                sxy[pos] = R3 * px + R4 * py + R5 * pz;
                sxz[pos] = R6 * px + R7 * py + R8 * pz;
            }
        }
        __syncthreads();
        const int nxc = s_nx;
        const int y0 = w * (MM / NWAVE);                // wave's 64-y stream

        for (int base = 0; base < nxc; base += 128) {   // typically one pass
            float px[2], py[2], pz[2], mn[2];
#pragma unroll
            for (int s = 0; s < 2; ++s) {
                int k = base + s * 64 + lane;
                bool a = (k < nxc);
                px[s] = a ? sxx[k] : SENT;
                py[s] = a ? sxy[k] : SENT;
                pz[s] = a ? sxz[k] : SENT;
                mn[s] = BIGV;
            }
            for (int j = 0; j < MM / NWAVE; j += 4) {   // wave-uniform broadcast b128
                float4 yx = *reinterpret_cast<const float4*>(syx + y0 + j);
                float4 yy = *reinterpret_cast<const float4*>(syy + y0 + j);
                float4 yz = *reinterpret_cast<const float4*>(syz + y0 + j);
#pragma unroll
                for (int s = 0; s < 2; ++s) {
                    float dx0 = px[s] - yx.x, dy0 = py[s] - yy.x, dz0 = pz[s] - yz.x;
                    float dx1 = px[s] - yx.y, dy1 = py[s] - yy.y, dz1 = pz[s] - yz.y;
                    float dx2 = px[s] - yx.z, dy2 = py[s] - yy.z, dz2 = pz[s] - yz.z;
                    float dx3 = px[s] - yx.w, dy3 = py[s] - yy.w, dz3 = pz[s] - yz.w;
                    float d0 = dx0 * dx0 + dy0 * dy0 + dz0 * dz0;
                    float d1 = dx1 * dx1 + dy1 * dy1 + dz1 * dz1;
                    float d2 = dx2 * dx2 + dy2 * dy2 + dz2 * dz2;
                    float d3 = dx3 * dx3 + dy3 * dy3 + dz3 * dz3;
                    mn[s] = fminf(mn[s], fminf(fminf(d0, d1), fminf(d2, d3)));
                }
            }
#pragma unroll
            for (int s = 0; s < 2; ++s) pmin[w][s * 64 + lane] = mn[s];
            __syncthreads();
            if (tid < 128 && base + tid < nxc) {
                float m = pmin[0][tid];
#pragma unroll
                for (int ww = 1; ww < NWAVE; ++ww) m = fminf(m, pmin[ww][tid]);
                sum += m;
            }
            __syncthreads();
        }

        for (int off = 32; off > 0; off >>= 1) sum += __shfl_down(sum, off);
        if (lane == 0) red[w] = sum;
        __syncthreads();
        if (tid == 0) {
            float tot = 0.0f;
            for (int ww = 0; ww < NWAVE; ++ww) tot += red[ww];
            g_ws[(0 + z) * PB + pb] = tot;              // qual partial
            g_ws[(8 + z) * PB + pb] = (float)s_nx;      // nx partial
        }
    } else {
        // ---------------- coverage y-chunk c ----------------
        const int c = z - QCHUNKS;
        if (tid < CCH) {                                // stage 128 y (waves 0-1, full)
            const float* y = opt + (optbase + c * CCH + tid) * 3;
            float yx = y[0], yy = y[1], yz = y[2];
            bool v = (yx != 0.0f) | (yy != 0.0f) | (yz != 0.0f);
            if (!v) { yx = SENT; yy = SENT; yz = SENT; }
            syx[tid] = yx; syy[tid] = yy; syz[tid] = yz;
            unsigned long long bal = __ballot(v);
            if (lane == 0) atomicAdd(&s_ny, __popcll(bal));
        }
        for (int n = tid; n < NN; n += THREADS) {       // compact FULL x of part i
            const float* p = ipt + ((size_t)b * NN + n) * 3;
            float px = p[0], py = p[1], pz = p[2];
            bool nz = (px != 0.0f) | (py != 0.0f) | (pz != 0.0f);
            bool sel = nz && (idx[b * NN + n] == i);
            int pos = wave_compact_slot(sel, &s_nx, lane);
            if (sel) {
                px -= t0; py -= t1; pz -= t2;
                sxx[pos] = R0 * px + R1 * py + R2 * pz;
                sxy[pos] = R3 * px + R4 * py + R5 * pz;
                sxz[pos] = R6 * px + R7 * py + R8 * pz;
            }
        }
        __syncthreads();
        const int nx = s_nx;
        const int ny = s_ny;
        const int nx32 = (nx + 31) & ~31;               // 8 wave-slices, each %4==0
        if (tid < nx32 - nx) {
            sxx[nx + tid] = SENT; sxy[nx + tid] = SENT; sxz[nx + tid] = SENT;
        }
        __syncthreads();

        float qx[2], qy[2], qz[2], mn[2];
#pragma unroll
        for (int s = 0; s < 2; ++s) {                   // lane's 2 y slots
            int j = s * 64 + lane;
            qx[s] = syx[j]; qy[s] = syy[j]; qz[s] = syz[j];
            mn[s] = BIGV;
        }
        const int q = nx32 / NWAVE;
        const int x0 = w * q;
        for (int k = 0; k < q; k += 4) {                // wave-uniform broadcast b128
            float4 xx = *reinterpret_cast<const float4*>(sxx + x0 + k);
            float4 xy = *reinterpret_cast<const float4*>(sxy + x0 + k);
            float4 xz = *reinterpret_cast<const float4*>(sxz + x0 + k);
#pragma unroll
            for (int s = 0; s < 2; ++s) {
                float dx0 = qx[s] - xx.x, dy0 = qy[s] - xy.x, dz0 = qz[s] - xz.x;
                float dx1 = qx[s] - xx.y, dy1 = qy[s] - xy.y, dz1 = qz[s] - xz.y;
                float dx2 = qx[s] - xx.z, dy2 = qy[s] - xy.z, dz2 = qz[s] - xz.z;
                float dx3 = qx[s] - xx.w, dy3 = qy[s] - xy.w, dz3 = qz[s] - xz.w;
                float d0 = dx0 * dx0 + dy0 * dy0 + dz0 * dz0;
                float d1 = dx1 * dx1 + dy1 * dy1 + dz1 * dz1;
                float d2 = dx2 * dx2 + dy2 * dy2 + dz2 * dz2;
                float d3 = dx3 * dx3 + dy3 * dy3 + dz3 * dz3;
                mn[s] = fminf(mn[s], fminf(fminf(d0, d1), fminf(d2, d3)));
            }
        }
#pragma unroll
        for (int s = 0; s < 2; ++s) pmin[w][s * 64 + lane] = mn[s];   // BIGV if q==0
        __syncthreads();
        if (tid < CCH && syx[tid] != SENT) {            // valid y only
            float m = pmin[0][tid];
#pragma unroll
            for (int ww = 1; ww < NWAVE; ++ww) m = fminf(m, pmin[ww][tid]);
            sum += m;                                   // nx==0 -> BIGV, gated in finalize
        }
        __syncthreads();

        for (int off = 32; off > 0; off >>= 1) sum += __shfl_down(sum, off);
        if (lane == 0) red[w] = sum;
        __syncthreads();
        if (tid == 0) {
            float tot = 0.0f;
            for (int ww = 0; ww < NWAVE; ++ww) tot += red[ww];
            g_ws[(4 + c) * PB + pb] = tot;              // cov partial
            g_ws[(12 + c) * PB + pb] = (float)ny;       // ny partial
        }
    }
}

__global__ __launch_bounds__(256) void finalize_kernel(
    const float* __restrict__ probs,   // (P,B,1)
    const float* __restrict__ mu,      // (B,DLAT)
    const float* __restrict__ logvar,  // (B,DLAT)
    float* __restrict__ out)
{
    const int tid = threadIdx.x;
    __shared__ float red[4];
    __shared__ float s_wq[PB], s_wc[PB], s_val[PB];

    // KL over B*DLAT, float4-vectorized
    const float4* mu4 = reinterpret_cast<const float4*>(mu);
    const float4* lv4 = reinterpret_cast<const float4*>(logvar);
    float kls = 0.0f;
    for (int t = tid; t < BB * DLAT / 4; t += 256) {
        float4 m4 = mu4[t], l4 = lv4[t];
        kls += (1.0f + l4.x - m4.x * m4.x - expf(l4.x))
             + (1.0f + l4.y - m4.y * m4.y - expf(l4.y))
             + (1.0f + l4.z - m4.z * m4.z - expf(l4.z))
             + (1.0f + l4.w - m4.w * m4.w - expf(l4.w));
    }
    for (int off = 32; off > 0; off >>= 1) kls += __shfl_down(kls, off);
    if ((tid & 63) == 0) red[tid >> 6] = kls;

    if (tid < PB) {
        float qs  = g_ws[0 * PB + tid] + g_ws[1 * PB + tid] + g_ws[2 * PB + tid] + g_ws[3 * PB + tid];
        float cs  = g_ws[4 * PB + tid] + g_ws[5 * PB + tid] + g_ws[6 * PB + tid] + g_ws[7 * PB + tid];
        float nxf = g_ws[8 * PB + tid] + g_ws[9 * PB + tid] + g_ws[10 * PB + tid] + g_ws[11 * PB + tid];
        float nyf = g_ws[12 * PB + tid] + g_ws[13 * PB + tid] + g_ws[14 * PB + tid] + g_ws[15 * PB + tid];
        bool valid = (nxf > 0.0f) && (nyf > 0.0f);
        float wgt = valid ? probs[tid] : 0.0f;
        s_wq[tid] = wgt * (qs / fmaxf(nxf, 1.0f));
        s_wc[tid] = wgt * (cs / fmaxf(nyf, 1.0f));
        s_val[tid] = valid ? 1.0f : 0.0f;
    }
    __syncthreads();

    if (tid == 0) {
        float kld = -0.5f * (red[0] + red[1] + red[2] + red[3]) / (float)BB;
        float ch = 0.0f, cov = 0.0f, qu = 0.0f, num = 0.0f;
        for (int ii = 0; ii < PP; ++ii) {
            float sq = 0.0f, sc = 0.0f, n = 0.0f;
            for (int bb = 0; bb < BB; ++bb) {
                sq += s_wq[ii * BB + bb];
                sc += s_wc[ii * BB + bb];
                n += s_val[ii * BB + bb];
            }
            float has = (n > 0.0f) ? 1.0f : 0.0f;
            float invn = has / fmaxf(n, 1.0f);
            qu += sq * invn;
            cov += sc * invn;
            ch += (sq + sc) * invn;
            num += has;
        }
        float invnum = 1.0f / fmaxf(num, 1.0f);
        float cds = ch * invnum;
        out[0] = cds + BETA_C * kld;
        out[1] = cds;
        out[2] = cov * invnum;
        out[3] = qu * invnum;
        out[4] = kld;
    }
}

extern "C" void kernel_launch(void* const* d_in, const int* in_sizes, int n_in,
                              void* d_out, int out_size, void* d_ws, size_t ws_size,
                              hipStream_t stream) {
    const float* ipt    = (const float*)d_in[0];
    const float* opt    = (const float*)d_in[1];
    const float* trans  = (const float*)d_in[2];
    const float* rots   = (const float*)d_in[3];
    const float* probs  = (const float*)d_in[4];
    const int*   idx    = (const int*)d_in[5];
    const float* mu     = (const float*)d_in[6];
    const float* logvar = (const float*)d_in[7];
    float* out = (float*)d_out;
    (void)d_ws; (void)ws_size; (void)in_sizes; (void)n_in; (void)out_size;

    dim3 grid(BB, PP, QCHUNKS + CCHUNKS);
    parts_kernel<<<grid, THREADS, 0, stream>>>(ipt, opt, trans, rots, idx);
    finalize_kernel<<<1, 256, 0, stream>>>(probs, mu, logvar, out);
}